// Round 6
// baseline (178.548 us; speedup 1.0000x reference)
//
#include <hip/hip_runtime.h>

// Problem constants (from reference):
//   x:       [B=16, E=64, S=32768] float32
//   indices: [B=16, E=64] int (values in [0, S/STEP))
//   out:     [B, 1, S] float32  -> flat B*S
// out[b,s] = sum_e x[b, e, s - idx[b,e]*STEP]  where idx*STEP <= s
constexpr int B = 16;
constexpr int E = 64;
constexpr int S = 32768;
constexpr int STEP = 256;
constexpr int HALF = 512;   // samples per half-tile (128 threads * float4)
constexpr int CH = 8;       // loads in flight per thread in the main loop

// te is a multiple of 256 and each wave spans exactly 256 consecutive
// samples, so "event in-range" is wave-uniform. Sorting events by te lets
// each wave process only the prefix of in-range events: no dummy clamped
// loads (was ~50% of VMEM instrs), no mask FMAs.
// Pairing half-tile pr with 63-pr keeps per-block real-load count constant.
__global__ __launch_bounds__(256)
void sparse_audio_gather(const float* __restrict__ x,
                         const int* __restrict__ idx,
                         float* __restrict__ out) {
    const int b     = blockIdx.y;
    const int pr    = blockIdx.x;                  // 0..31
    const int half  = (threadIdx.x < 128) ? pr : (63 - pr);
    const int local = (int)(threadIdx.x & 127);
    const int s0    = half * HALF + local * 4;     // < S
    const int wb    = s0 & ~255;                   // wave-uniform base

    // Sort events by te (rank-based counting sort, packed (te<<6)|e).
    __shared__ int t_raw[E];
    __shared__ int t_sorted[E];
    if (threadIdx.x < E) {
        t_raw[threadIdx.x] = idx[b * E + (int)threadIdx.x] * STEP;
    }
    __syncthreads();
    if (threadIdx.x < E) {
        const int te = t_raw[threadIdx.x];
        int rank = 0;
        #pragma unroll
        for (int j = 0; j < E; ++j) {
            const int tj = t_raw[j];
            rank += (tj < te) || (tj == te && j < (int)threadIdx.x);
        }
        t_sorted[rank] = (te << 6) | (int)threadIdx.x;
    }
    __syncthreads();

    // Wave-uniform count of in-range events (sorted prefix length).
    int nw = 0;
    #pragma unroll
    for (int j = 0; j < E; ++j) {
        nw += ((t_sorted[j] >> 6) <= wb);
    }

    const float* xb = x + (size_t)b * E * S;
    float4 acc = make_float4(0.f, 0.f, 0.f, 0.f);

    // Main loop: unconditional 8-deep batches over the in-range prefix.
    int j = 0;
    for (; j + CH <= nw; j += CH) {
        float4 v[CH];
        #pragma unroll
        for (int k = 0; k < CH; ++k) {
            const int p  = t_sorted[j + k];
            const int e  = p & 63;
            const int off = s0 - (p >> 6);         // >= 0 guaranteed
            v[k] = *reinterpret_cast<const float4*>(xb + (size_t)e * S + off);
        }
        #pragma unroll
        for (int k = 0; k < CH; ++k) {
            acc.x += v[k].x;
            acc.y += v[k].y;
            acc.z += v[k].z;
            acc.w += v[k].w;
        }
    }

    // Tail: one masked clamp batch (rem <= 7).
    {
        float4 v[CH];
        float  m[CH];
        #pragma unroll
        for (int k = 0; k < CH; ++k) {
            const int jj  = (j + k < E) ? (j + k) : (E - 1);
            const int p   = t_sorted[jj];
            const int e   = p & 63;
            const int off = s0 - (p >> 6);
            const int offc = off < 0 ? 0 : off;
            m[k] = (j + k < nw) ? 1.0f : 0.0f;
            v[k] = *reinterpret_cast<const float4*>(xb + (size_t)e * S + offc);
        }
        #pragma unroll
        for (int k = 0; k < CH; ++k) {
            acc.x += m[k] * v[k].x;
            acc.y += m[k] * v[k].y;
            acc.z += m[k] * v[k].z;
            acc.w += m[k] * v[k].w;
        }
    }

    *reinterpret_cast<float4*>(out + (size_t)b * S + s0) = acc;
}

extern "C" void kernel_launch(void* const* d_in, const int* in_sizes, int n_in,
                              void* d_out, int out_size, void* d_ws, size_t ws_size,
                              hipStream_t stream) {
    const float* x   = (const float*)d_in[0];
    const int*   idx = (const int*)d_in[1];
    float*       out = (float*)d_out;

    dim3 grid(S / (2 * HALF), B);   // (32, 16) — each block does 2 half-tiles
    dim3 block(256);
    sparse_audio_gather<<<grid, block, 0, stream>>>(x, idx, out);
}

// Round 7
// 176.899 us; speedup vs baseline: 1.0093x; 1.0093x over previous
//
#include <hip/hip_runtime.h>

// Problem constants (from reference):
//   x:       [B=16, E=64, S=32768] float32
//   indices: [B=16, E=64] int (values in [0, S/STEP))
//   out:     [B, 1, S] float32  -> flat B*S
// out[b,s] = sum_e x[b, e, s - idx[b,e]*STEP]  where idx*STEP <= s
//
// Final design (best measured: 175.6 us, absmax 0):
//  - scatter inverted to gather: each output element is an independent
//    64-term sum, no atomics
//  - unconditional clamped loads + multiplicative mask -> 16 loads in
//    flight per thread before any s_waitcnt (R0->R1: 197->176 us)
//  - half-tile pairing (pr with 63-pr) balances per-block HBM demand
//  - tested and rejected: E-split occupancy boost (R2, +9 us = its extra
//    traffic), sorted-prefix VMEM halving (R5, neutral) -> kernel is at
//    the HBM-pattern floor (~15 us vs ~12 us demand); dur_us is dominated
//    by ~160 us of fixed harness restore/poison work.
constexpr int B = 16;
constexpr int E = 64;
constexpr int S = 32768;
constexpr int STEP = 256;
constexpr int HALF = 512;      // samples per half-tile
constexpr int GRP  = 16;       // loads in flight per thread

__global__ __launch_bounds__(256)
void sparse_audio_gather(const float* __restrict__ x,
                         const int* __restrict__ idx,
                         float* __restrict__ out) {
    const int b     = blockIdx.y;
    const int pr    = blockIdx.x;                       // 0..31
    const int lo    = (threadIdx.x < 128);              // wave-uniform
    const int half  = lo ? pr : (63 - pr);
    const int local = (int)(threadIdx.x & 127);
    const int s0    = half * HALF + local * 4;          // < S always

    // Stage the 64 per-batch event offsets (block-uniform) in LDS.
    __shared__ int t_lds[E];
    if (threadIdx.x < E) {
        t_lds[threadIdx.x] = idx[b * E + (int)threadIdx.x] * STEP;
    }
    __syncthreads();

    const float* xb = x + (size_t)b * E * S;

    float4 acc = make_float4(0.f, 0.f, 0.f, 0.f);

    // Unconditional clamped loads (address max(s0-te,0) is always in
    // [0, s0] subset [0, S-4]), masked after the fact: GRP loads issue
    // back-to-back before any s_waitcnt -> 16 outstanding per thread.
    for (int e0 = 0; e0 < E; e0 += GRP) {
        float4 v[GRP];
        float  m[GRP];
        #pragma unroll
        for (int j = 0; j < GRP; ++j) {
            const int off  = s0 - t_lds[e0 + j];
            const int offc = off < 0 ? 0 : off;
            m[j] = off < 0 ? 0.0f : 1.0f;
            v[j] = *reinterpret_cast<const float4*>(
                       xb + (size_t)(e0 + j) * S + offc);
        }
        #pragma unroll
        for (int j = 0; j < GRP; ++j) {
            acc.x += m[j] * v[j].x;
            acc.y += m[j] * v[j].y;
            acc.z += m[j] * v[j].z;
            acc.w += m[j] * v[j].w;
        }
    }

    *reinterpret_cast<float4*>(out + (size_t)b * S + s0) = acc;
}

extern "C" void kernel_launch(void* const* d_in, const int* in_sizes, int n_in,
                              void* d_out, int out_size, void* d_ws, size_t ws_size,
                              hipStream_t stream) {
    const float* x   = (const float*)d_in[0];
    const int*   idx = (const int*)d_in[1];
    float*       out = (float*)d_out;

    dim3 grid(S / (2 * HALF), B);   // (32, 16) — each block does 2 half-tiles
    dim3 block(256);
    sparse_audio_gather<<<grid, block, 0, stream>>>(x, idx, out);
}